// Round 15
// baseline (141.489 us; speedup 1.0000x reference)
//
#include <hip/hip_runtime.h>
#include <math.h>

#define B_ 4
#define D_ 32
#define H_ 192
#define W_ 192
#define HW_ (H_ * W_)

#define NT 5            // Taylor terms p = 1..5

#define TW 48           // 12 real col-groups (q=2..13); 16 staged quads
#define TH 12
#define NTHR 192        // 12 rows x 16 quads, one item per thread
#define ZCHUNK 16       // 512 blocks -> 2 blocks/CU (measured slot optimum)
#define NP (ZCHUNK + 8) // 24 planes p = 0..23
#define NITER (NP / 2)  // 12 iterations, 2 planes per barrier

#define XT_H 26         // TH + 14
#define XT_W 64         // 16 quads: staged cols = global [w0-8, w0+55]
#define XT_SZ (XT_H * XT_W)   // 1664 words
#define XT_Q (XT_H * 16)      // 416 staged quads

#define SMEM_WORDS (4 * XT_SZ)   // 6656 words = 26.6 KB (4 rotating buffers)

#define NTAPS (B_ * 9 * 15 * 15)
#define WS_FLOATS (B_ * 65)      // per-batch coefficient table in d_ws

__device__ inline float4 f4fma(float c, float4 a, float4 d) {
    d.x = fmaf(c, a.x, d.x); d.y = fmaf(c, a.y, d.y);
    d.z = fmaf(c, a.z, d.z); d.w = fmaf(c, a.w, d.w);
    return d;
}
__device__ inline float4 f4add(float4 a, float4 b) {
    a.x += b.x; a.y += b.y; a.z += b.z; a.w += b.w; return a;
}
__device__ inline float rfl(float x) {
    return __int_as_float(__builtin_amdgcn_readfirstlane(__float_as_int(x)));
}
// lane l <- lane l+N within each 16-lane DPP row; OOB -> 0. (HW-verified R5)
template<int N>
__device__ inline float dpp_shl(float v) {
    return __int_as_float(__builtin_amdgcn_update_dpp(
        0, __float_as_int(v), 0x100 | N, 0xF, 0xF, true));
}
// lane l <- lane l-N within each 16-lane DPP row; OOB -> 0.
template<int N>
__device__ inline float dpp_shr(float v) {
    return __int_as_float(__builtin_amdgcn_update_dpp(
        0, __float_as_int(v), 0x110 | N, 0xF, 0xF, true));
}

__device__ inline float tap_val(int idx, const float* bet_xy,
                                const float* bet_z, const float* alpha) {
    const float INV = 0.3989422804014327f;
    int bb = idx / 2025;
    int r  = idx % 2025;
    int dz = r / 225;
    int r2 = r % 225;
    int dh = r2 / 15;
    int dw = r2 % 15;
    float bxy = bet_xy[bb], bzv = bet_z[bb], al = alpha[bb];
    float zd = (float)(dz - 4), hd = (float)(dh - 7), wd = (float)(dw - 7);
    float az = expf(-zd * zd / (2.f * bzv * bzv)) * (INV / bzv);
    float gh = expf(-hd * hd / (2.f * bxy * bxy)) * (INV / bxy);
    float gw = expf(-wd * wd / (2.f * bxy * bxy)) * (INV / bxy);
    return 1.f - expf(-al * az * gh * gw);
}

__device__ inline float ct_val(int bb, int n, int k, float S,
                               const float* bet_xy, const float* bet_z,
                               const float* alpha) {
    const float INV = 0.3989422804014327f;
    float bxy = bet_xy[bb], bzv = bet_z[bb], al = alpha[bb];
    if (k < 8) {
        float d = (float)k;
        float g = expf(-d * d / (2.f * bxy * bxy)) * (INV / bxy);
        float p = g;
        for (int q = 0; q < n; ++q) p *= g;
        return p;
    } else {
        float d = (float)(k - 8);
        float az = expf(-d * d / (2.f * bzv * bzv)) * (INV / bzv);
        float base = al * az;
        float p = base;
        for (int q = 0; q < n; ++q) p *= base;
        const float facs[NT] = {1.f, 2.f, 6.f, 24.f, 120.f};
        float sign = (n & 1) ? -1.f : 1.f;
        return sign * p / (facs[n] * S);
    }
}

// One small block: exact tap-sum S + all 4 batches' 65-entry coefficient
// tables -> d_ws.
__global__ __launch_bounds__(1024)
void psf_precompute(const float* __restrict__ bet_xy,
                    const float* __restrict__ bet_z,
                    const float* __restrict__ alpha,
                    float* __restrict__ ws) {
    __shared__ float red[1024];
    const int t = threadIdx.x;
    float local = 0.f;
#pragma unroll
    for (int s = 0; s < 8; ++s) {
        int idx = t + s * 1024;
        if (idx < NTAPS) local += tap_val(idx, bet_xy, bet_z, alpha);
    }
    red[t] = local;
    __syncthreads();
    for (int s = 512; s > 0; s >>= 1) {
        if (t < s) red[t] += red[t + s];
        __syncthreads();
    }
    const float S = red[0];
    if (t < WS_FLOATS) {
        int bb = t / 65, j = t % 65;
        ws[t] = ct_val(bb, j / 13, j % 13, S, bet_xy, bet_z, alpha);
    }
}

// Fully fused separable-Taylor blur, R13 structure (2 planes/barrier, 4
// rotating xt buffers, scalar math) with BATCHED READS: all 30 ds_read_b128
// (both planes) issue right after the barrier, both fold to ctr/sp windows,
// then computeA/storeA/computeB/storeB run register-resident — one lgkmcnt
// latency cascade per iteration instead of two. hr[n] for all 5 terms is
// computed before any DPP use (breaks hr->DPP forwarding hazards).
// __launch_bounds__(192,2) caps VGPR at 256 (we need 2 waves/SIMD).
template<bool USE_WS>
__global__ __launch_bounds__(NTHR, 2)
void conv_kernel(const float* __restrict__ x,
                 const float* __restrict__ bet_xy,
                 const float* __restrict__ bet_z,
                 const float* __restrict__ alpha,
                 const float* __restrict__ ct_ws,
                 float* __restrict__ out) {
    __shared__ __align__(16) float smem[SMEM_WORDS];
    float* xtb = smem;                 // [4][XT_SZ]
    float* red = smem;                 // alias: pre-loop only
    float* ct  = smem;                 // alias: pre-loop only, [65]

    const int t  = threadIdx.x;
    const int w0 = blockIdx.x * TW;
    const int h0 = blockIdx.y * TH;
    const int bz = blockIdx.z;
    const int b  = bz & 3;
    const int z0 = (bz >> 2) * ZCHUNK;
    const float4 z4 = make_float4(0.f, 0.f, 0.f, 0.f);

    // ---- coefficient table (65 values for batch b) into LDS ----
    if (USE_WS) {
        if (t < 65) ct[t] = ct_ws[b * 65 + t];
        __syncthreads();
    } else {
        float local = 0.f;
#pragma unroll
        for (int s = 0; s < 43; ++s) {
            int idx = t + s * NTHR;
            if (idx < NTAPS) local += tap_val(idx, bet_xy, bet_z, alpha);
        }
        red[t] = local;
        __syncthreads();
        for (int s = 128; s > 0; s >>= 1) {
            if (t < s && t + s < NTHR) red[t] += red[t + s];
            __syncthreads();
        }
        const float S = red[0];
        __syncthreads();
        if (t < 65) ct[t] = ct_val(b, t / 13, t % 13, S, bet_xy, bet_z, alpha);
        __syncthreads();
    }

    // ---- hoist coefficients to wave-uniform scalars (SGPRs) ----
    float cg_[NT][8], cz_[NT][5];
#pragma unroll
    for (int n = 0; n < NT; ++n) {
#pragma unroll
        for (int k = 0; k < 8; ++k) cg_[n][k] = rfl(ct[n * 13 + k]);
#pragma unroll
        for (int k = 0; k < 5; ++k) cz_[n][k] = rfl(ct[n * 13 + 8 + k]);
    }
    __syncthreads();   // ct reads done before xt staging overwrites alias

    // ---- staging descriptors: 416 quads, float4-aligned, zero-filled OOB ----
    const float* xb = x + (size_t)b * (D_ * HW_);
    int goff[3];
#pragma unroll
    for (int k = 0; k < 3; ++k) {
        int i = t + NTHR * k;
        if (i < XT_Q) {
            int row = i >> 4, qq = i & 15;
            int gh = h0 + row - 7, gc = w0 - 8 + 4 * qq;
            bool ok = (gh >= 0) && (gh < H_) && (gc >= 0) && (gc <= W_ - 4);
            goff[k] = ok ? (gh * W_ + gc) : -1;
        } else {
            goff[k] = -2;   // no item (k==2, t>=32)
        }
    }
    // stage one plane into buffer bi (registers -> LDS, guarded)
    auto stage = [&](int zi, int bi) {
        if (zi >= 0 && zi < D_) {
            const float* xp = xb + (size_t)zi * HW_;
            float4* xn = (float4*)(xtb + bi * XT_SZ);
            xn[t]       = (goff[0] >= 0) ? *(const float4*)(xp + goff[0]) : z4;
            xn[t + 192] = (goff[1] >= 0) ? *(const float4*)(xp + goff[1]) : z4;
            if (goff[2] != -2)
                xn[t + 384] = (goff[2] >= 0) ? *(const float4*)(xp + goff[2]) : z4;
        }
    };
    // pre-stage planes p=0,1 (zi = z0-4, z0-3) into buffers 0,1
    stage(z0 - 4, 0);
    stage(z0 - 3, 1);

    // ---- per-thread item ----
    const int r1 = t >> 4;          // tile row 0..11
    const int q  = t & 15;          // quad 0..15 (== lane&15: DPP row-aligned)
    const bool qreal = (q >= 2) && (q <= 13);   // real output quads

    float4 acc[9];
#pragma unroll
    for (int k = 0; k < 9; ++k) acc[k] = z4;

    // fused h-conv + w-conv + z-scatter from a folded window (ctr, sp)
    auto compute_plane = [&](const float4& ctr, const float4 (&sp)[7]) {
        // 1) all 5 terms' h-conv results first (pure FMA, no DPP hazards)
        float4 hrs[NT];
#pragma unroll
        for (int n = 0; n < NT; ++n) {
            float c0 = cg_[n][0];
            float4 hr;
            hr.x = c0 * ctr.x; hr.y = c0 * ctr.y;
            hr.z = c0 * ctr.z; hr.w = c0 * ctr.w;
#pragma unroll
            for (int k = 1; k <= 7; ++k) hr = f4fma(cg_[n][k], sp[k - 1], hr);
            hrs[n] = hr;
        }
        // 2) per-term DPP window + w-conv + z-weights
        float4 u[5];
#pragma unroll
        for (int n = 0; n < NT; ++n) {
            float4 hr = hrs[n];
            float win[20];
            win[8]  = hr.x; win[9]  = hr.y; win[10] = hr.z; win[11] = hr.w;
            win[0]  = dpp_shr<2>(hr.x); win[1]  = dpp_shr<2>(hr.y);
            win[2]  = dpp_shr<2>(hr.z); win[3]  = dpp_shr<2>(hr.w);
            win[4]  = dpp_shr<1>(hr.x); win[5]  = dpp_shr<1>(hr.y);
            win[6]  = dpp_shr<1>(hr.z); win[7]  = dpp_shr<1>(hr.w);
            win[12] = dpp_shl<1>(hr.x); win[13] = dpp_shl<1>(hr.y);
            win[14] = dpp_shl<1>(hr.z); win[15] = dpp_shl<1>(hr.w);
            win[16] = dpp_shl<2>(hr.x); win[17] = dpp_shl<2>(hr.y);
            win[18] = dpp_shl<2>(hr.z); win[19] = dpp_shl<2>(hr.w);
            float c0 = cg_[n][0];
            float4 qv;
            qv.x = c0 * win[8];  qv.y = c0 * win[9];
            qv.z = c0 * win[10]; qv.w = c0 * win[11];
#pragma unroll
            for (int k = 1; k <= 7; ++k) {
                float c = cg_[n][k];
                qv.x = fmaf(c, win[8 - k]  + win[8 + k],  qv.x);
                qv.y = fmaf(c, win[9 - k]  + win[9 + k],  qv.y);
                qv.z = fmaf(c, win[10 - k] + win[10 + k], qv.z);
                qv.w = fmaf(c, win[11 - k] + win[11 + k], qv.w);
            }
            if (n == 0) {
#pragma unroll
                for (int j = 0; j < 5; ++j) {
                    float cz = cz_[0][j];
                    u[j].x = cz * qv.x; u[j].y = cz * qv.y;
                    u[j].z = cz * qv.z; u[j].w = cz * qv.w;
                }
            } else {
#pragma unroll
                for (int j = 0; j < 5; ++j)
                    u[j] = f4fma(cz_[n][j], qv, u[j]);
            }
        }
        acc[4] = f4add(acc[4], u[0]);
#pragma unroll
        for (int j = 1; j <= 4; ++j) {
            acc[4 + j] = f4add(acc[4 + j], u[j]);
            acc[4 - j] = f4add(acc[4 - j], u[j]);
        }
    };
    // store completed plane p (output z = z0 + p - 8), then advance the ring
    auto store_shift = [&](int p) {
        if (p >= 8 && qreal) {
            int z = z0 + (p - 8);
            size_t o = ((size_t)(b * D_ + z) * H_ + (h0 + r1)) * W_ + (w0 - 8 + 4 * q);
            *(float4*)&out[o] = acc[0];
        }
#pragma unroll
        for (int k = 0; k < 8; ++k) acc[k] = acc[k + 1];
        acc[8] = z4;
    };

#pragma unroll 1
    for (int i = 0; i < NITER; ++i) {
        __syncthreads();   // pair (i&1) staged; pair ((i+1)&1) free

        const int pA = 2 * i;
        const int ziA = z0 - 4 + pA;
        const int bA = (i & 1) * 2;
        const int znC = ziA + 2, znD = ziA + 3;
        const bool vC = (pA + 2 < NP) && (znC >= 0) && (znC < D_);
        const bool vD = (pA + 3 < NP) && (znD >= 0) && (znD < D_);
        const bool doA = (ziA >= 0) && (ziA < D_);
        const bool doB = (ziA + 1 >= 0) && (ziA + 1 < D_);

        // prefetch next two planes into registers (hidden under this iter)
        float4 cv0, cv1, cv2, dv0, dv1, dv2;
        if (vC) {
            const float* xp = xb + (size_t)znC * HW_;
            cv0 = (goff[0] >= 0) ? *(const float4*)(xp + goff[0]) : z4;
            cv1 = (goff[1] >= 0) ? *(const float4*)(xp + goff[1]) : z4;
            cv2 = z4;
            if (goff[2] >= 0) cv2 = *(const float4*)(xp + goff[2]);
        }
        if (vD) {
            const float* xp = xb + (size_t)znD * HW_;
            dv0 = (goff[0] >= 0) ? *(const float4*)(xp + goff[0]) : z4;
            dv1 = (goff[1] >= 0) ? *(const float4*)(xp + goff[1]) : z4;
            dv2 = z4;
            if (goff[2] >= 0) dv2 = *(const float4*)(xp + goff[2]);
        }

        // ---- batched LDS reads: BOTH planes' 15 rows issue up front ----
        // (reads from an unstaged buffer are harmless: compute is guarded)
        const float4* xA = (const float4*)(xtb + bA * XT_SZ) + t;
        const float4* xB = xA + (XT_SZ / 4);
        float4 rvA[15], rvB[15];
#pragma unroll
        for (int k = 0; k < 15; ++k) rvA[k] = xA[k * 16];
#pragma unroll
        for (int k = 0; k < 15; ++k) rvB[k] = xB[k * 16];
        float4 ctrA = rvA[7], ctrB = rvB[7];
        float4 spA[7], spB[7];
#pragma unroll
        for (int k = 1; k <= 7; ++k) {
            spA[k - 1] = f4add(rvA[7 - k], rvA[7 + k]);
            spB[k - 1] = f4add(rvB[7 - k], rvB[7 + k]);
        }

        // two plane pipelines, fully register-resident after the folds
        if (doA) compute_plane(ctrA, spA);
        store_shift(pA);
        if (doB) compute_plane(ctrB, spB);
        store_shift(pA + 1);

        // write prefetched planes into the other buffer pair
        const int bC = ((i + 1) & 1) * 2;
        if (vC) {
            float4* xn = (float4*)(xtb + bC * XT_SZ);
            xn[t] = cv0; xn[t + 192] = cv1;
            if (goff[2] != -2) xn[t + 384] = cv2;
        }
        if (vD) {
            float4* xn = (float4*)(xtb + (bC + 1) * XT_SZ);
            xn[t] = dv0; xn[t + 192] = dv1;
            if (goff[2] != -2) xn[t + 384] = dv2;
        }
    }
}

extern "C" void kernel_launch(void* const* d_in, const int* in_sizes, int n_in,
                              void* d_out, int out_size, void* d_ws, size_t ws_size,
                              hipStream_t stream) {
    const float* x      = (const float*)d_in[0];
    const float* bet_xy = (const float*)d_in[1];
    const float* bet_z  = (const float*)d_in[2];
    const float* alpha  = (const float*)d_in[3];
    float* out = (float*)d_out;

    dim3 grid(W_ / TW, H_ / TH, B_ * (D_ / ZCHUNK));
    if (d_ws != nullptr && ws_size >= WS_FLOATS * sizeof(float)) {
        hipLaunchKernelGGL(psf_precompute, dim3(1), dim3(1024), 0, stream,
                           bet_xy, bet_z, alpha, (float*)d_ws);
        hipLaunchKernelGGL(HIP_KERNEL_NAME(conv_kernel<true>), grid, dim3(NTHR),
                           0, stream, x, bet_xy, bet_z, alpha,
                           (const float*)d_ws, out);
    } else {
        hipLaunchKernelGGL(HIP_KERNEL_NAME(conv_kernel<false>), grid, dim3(NTHR),
                           0, stream, x, bet_xy, bet_z, alpha,
                           (const float*)nullptr, out);
    }
}

// Round 16
// 130.308 us; speedup vs baseline: 1.0858x; 1.0858x over previous
//
#include <hip/hip_runtime.h>
#include <math.h>

#define B_ 4
#define D_ 32
#define H_ 192
#define W_ 192
#define HW_ (H_ * W_)

#define NT 5            // Taylor terms p = 1..5

#define TW 48           // 12 real col-groups (q=2..13); 16 staged quads
#define TH 12
#define NTHR 192        // 12 rows x 16 quads, one item per thread
#define ZCHUNK 16       // 512 blocks -> 2 blocks/CU (measured slot optimum)
#define NP (ZCHUNK + 8) // 24 planes p = 0..23
#define NITER (NP / 2)  // 12 iterations, 2 planes per barrier

#define XT_H 26         // TH + 14
#define XT_W 64         // 16 quads: staged cols = global [w0-8, w0+55]
#define XT_SZ (XT_H * XT_W)   // 1664 words
#define XT_Q (XT_H * 16)      // 416 staged quads

#define SMEM_WORDS (4 * XT_SZ)   // 6656 words = 26.6 KB (4 rotating buffers)

#define NTAPS (B_ * 9 * 15 * 15)
#define WS_FLOATS (B_ * 65)      // per-batch coefficient table in d_ws

// NOTE (R15 lesson): usable VGPR budget here is 256 (AGPR half unusable);
// this kernel compiles to 120 VGPR = 2 waves/SIMD. Do NOT add live state
// (>128 halves waves/SIMD or spills — both measured regressions).

__device__ inline float4 f4fma(float c, float4 a, float4 d) {
    d.x = fmaf(c, a.x, d.x); d.y = fmaf(c, a.y, d.y);
    d.z = fmaf(c, a.z, d.z); d.w = fmaf(c, a.w, d.w);
    return d;
}
__device__ inline float4 f4add(float4 a, float4 b) {
    a.x += b.x; a.y += b.y; a.z += b.z; a.w += b.w; return a;
}
__device__ inline float rfl(float x) {
    return __int_as_float(__builtin_amdgcn_readfirstlane(__float_as_int(x)));
}
// lane l <- lane l+N within each 16-lane DPP row; OOB -> 0. (HW-verified R5)
template<int N>
__device__ inline float dpp_shl(float v) {
    return __int_as_float(__builtin_amdgcn_update_dpp(
        0, __float_as_int(v), 0x100 | N, 0xF, 0xF, true));
}
// lane l <- lane l-N within each 16-lane DPP row; OOB -> 0.
template<int N>
__device__ inline float dpp_shr(float v) {
    return __int_as_float(__builtin_amdgcn_update_dpp(
        0, __float_as_int(v), 0x110 | N, 0xF, 0xF, true));
}

__device__ inline float tap_val(int idx, const float* bet_xy,
                                const float* bet_z, const float* alpha) {
    const float INV = 0.3989422804014327f;
    int bb = idx / 2025;
    int r  = idx % 2025;
    int dz = r / 225;
    int r2 = r % 225;
    int dh = r2 / 15;
    int dw = r2 % 15;
    float bxy = bet_xy[bb], bzv = bet_z[bb], al = alpha[bb];
    float zd = (float)(dz - 4), hd = (float)(dh - 7), wd = (float)(dw - 7);
    float az = expf(-zd * zd / (2.f * bzv * bzv)) * (INV / bzv);
    float gh = expf(-hd * hd / (2.f * bxy * bxy)) * (INV / bxy);
    float gw = expf(-wd * wd / (2.f * bxy * bxy)) * (INV / bxy);
    return 1.f - expf(-al * az * gh * gw);
}

__device__ inline float ct_val(int bb, int n, int k, float S,
                               const float* bet_xy, const float* bet_z,
                               const float* alpha) {
    const float INV = 0.3989422804014327f;
    float bxy = bet_xy[bb], bzv = bet_z[bb], al = alpha[bb];
    if (k < 8) {
        float d = (float)k;
        float g = expf(-d * d / (2.f * bxy * bxy)) * (INV / bxy);
        float p = g;
        for (int q = 0; q < n; ++q) p *= g;
        return p;
    } else {
        float d = (float)(k - 8);
        float az = expf(-d * d / (2.f * bzv * bzv)) * (INV / bzv);
        float base = al * az;
        float p = base;
        for (int q = 0; q < n; ++q) p *= base;
        const float facs[NT] = {1.f, 2.f, 6.f, 24.f, 120.f};
        float sign = (n & 1) ? -1.f : 1.f;
        return sign * p / (facs[n] * S);
    }
}

// One small block: exact tap-sum S + all 4 batches' 65-entry coefficient
// tables -> d_ws.
__global__ __launch_bounds__(1024)
void psf_precompute(const float* __restrict__ bet_xy,
                    const float* __restrict__ bet_z,
                    const float* __restrict__ alpha,
                    float* __restrict__ ws) {
    __shared__ float red[1024];
    const int t = threadIdx.x;
    float local = 0.f;
#pragma unroll
    for (int s = 0; s < 8; ++s) {
        int idx = t + s * 1024;
        if (idx < NTAPS) local += tap_val(idx, bet_xy, bet_z, alpha);
    }
    red[t] = local;
    __syncthreads();
    for (int s = 512; s > 0; s >>= 1) {
        if (t < s) red[t] += red[t + s];
        __syncthreads();
    }
    const float S = red[0];
    if (t < WS_FLOATS) {
        int bb = t / 65, j = t % 65;
        ws[t] = ct_val(bb, j / 13, j % 13, S, bet_xy, bet_z, alpha);
    }
}

// Fully fused separable-Taylor blur (best measured: 58.9-59.3 us dispatch):
//   2 planes per barrier, 4 rotating xt buffers, scalar float4 math.
//   Each thread owns one (row, quad): h-conv from xt (15 dense b128 reads),
//   w-conv via DPP row_shr/shl on the in-register h result (no LDS round
//   trip), z-scatter into a 9-deep output ring.
template<bool USE_WS>
__global__ __launch_bounds__(NTHR)
void conv_kernel(const float* __restrict__ x,
                 const float* __restrict__ bet_xy,
                 const float* __restrict__ bet_z,
                 const float* __restrict__ alpha,
                 const float* __restrict__ ct_ws,
                 float* __restrict__ out) {
    __shared__ __align__(16) float smem[SMEM_WORDS];
    float* xtb = smem;                 // [4][XT_SZ]
    float* red = smem;                 // alias: pre-loop only
    float* ct  = smem;                 // alias: pre-loop only, [65]

    const int t  = threadIdx.x;
    const int w0 = blockIdx.x * TW;
    const int h0 = blockIdx.y * TH;
    const int bz = blockIdx.z;
    const int b  = bz & 3;
    const int z0 = (bz >> 2) * ZCHUNK;
    const float4 z4 = make_float4(0.f, 0.f, 0.f, 0.f);

    // ---- coefficient table (65 values for batch b) into LDS ----
    if (USE_WS) {
        if (t < 65) ct[t] = ct_ws[b * 65 + t];
        __syncthreads();
    } else {
        float local = 0.f;
#pragma unroll
        for (int s = 0; s < 43; ++s) {
            int idx = t + s * NTHR;
            if (idx < NTAPS) local += tap_val(idx, bet_xy, bet_z, alpha);
        }
        red[t] = local;
        __syncthreads();
        for (int s = 128; s > 0; s >>= 1) {
            if (t < s && t + s < NTHR) red[t] += red[t + s];
            __syncthreads();
        }
        const float S = red[0];
        __syncthreads();
        if (t < 65) ct[t] = ct_val(b, t / 13, t % 13, S, bet_xy, bet_z, alpha);
        __syncthreads();
    }

    // ---- hoist coefficients to wave-uniform scalars (SGPRs) ----
    float cg_[NT][8], cz_[NT][5];
#pragma unroll
    for (int n = 0; n < NT; ++n) {
#pragma unroll
        for (int k = 0; k < 8; ++k) cg_[n][k] = rfl(ct[n * 13 + k]);
#pragma unroll
        for (int k = 0; k < 5; ++k) cz_[n][k] = rfl(ct[n * 13 + 8 + k]);
    }
    __syncthreads();   // ct reads done before xt staging overwrites alias

    // ---- staging descriptors: 416 quads, float4-aligned, zero-filled OOB ----
    const float* xb = x + (size_t)b * (D_ * HW_);
    int goff[3];
#pragma unroll
    for (int k = 0; k < 3; ++k) {
        int i = t + NTHR * k;
        if (i < XT_Q) {
            int row = i >> 4, qq = i & 15;
            int gh = h0 + row - 7, gc = w0 - 8 + 4 * qq;
            bool ok = (gh >= 0) && (gh < H_) && (gc >= 0) && (gc <= W_ - 4);
            goff[k] = ok ? (gh * W_ + gc) : -1;
        } else {
            goff[k] = -2;   // no item (k==2, t>=32)
        }
    }
    // stage one plane into buffer bi (registers -> LDS, guarded)
    auto stage = [&](int zi, int bi) {
        if (zi >= 0 && zi < D_) {
            const float* xp = xb + (size_t)zi * HW_;
            float4* xn = (float4*)(xtb + bi * XT_SZ);
            xn[t]       = (goff[0] >= 0) ? *(const float4*)(xp + goff[0]) : z4;
            xn[t + 192] = (goff[1] >= 0) ? *(const float4*)(xp + goff[1]) : z4;
            if (goff[2] != -2)
                xn[t + 384] = (goff[2] >= 0) ? *(const float4*)(xp + goff[2]) : z4;
        }
    };
    // pre-stage planes p=0,1 (zi = z0-4, z0-3) into buffers 0,1
    stage(z0 - 4, 0);
    stage(z0 - 3, 1);

    // ---- per-thread item ----
    const int r1 = t >> 4;          // tile row 0..11
    const int q  = t & 15;          // quad 0..15 (== lane&15: DPP row-aligned)
    const bool qreal = (q >= 2) && (q <= 13);   // real output quads

    float4 acc[9];
#pragma unroll
    for (int k = 0; k < 9; ++k) acc[k] = z4;

    // fused h-conv + w-conv + z-scatter of one plane (R7-proven scalar form)
    auto do_plane = [&](int zi, int bi) {
        if (zi < 0 || zi >= D_) return;
        const float4* x4 = (const float4*)(xtb + bi * XT_SZ) + t;
        float4 ctr = x4[7 * 16];
        float4 sp[7];
#pragma unroll
        for (int k = 1; k <= 7; ++k)
            sp[k - 1] = f4add(x4[(7 - k) * 16], x4[(7 + k) * 16]);
        float4 u[5];
#pragma unroll
        for (int n = 0; n < NT; ++n) {
            float c0 = cg_[n][0];
            float4 hr;
            hr.x = c0 * ctr.x; hr.y = c0 * ctr.y;
            hr.z = c0 * ctr.z; hr.w = c0 * ctr.w;
#pragma unroll
            for (int k = 1; k <= 7; ++k) hr = f4fma(cg_[n][k], sp[k - 1], hr);
            float win[20];
            win[8]  = hr.x; win[9]  = hr.y; win[10] = hr.z; win[11] = hr.w;
            win[0]  = dpp_shr<2>(hr.x); win[1]  = dpp_shr<2>(hr.y);
            win[2]  = dpp_shr<2>(hr.z); win[3]  = dpp_shr<2>(hr.w);
            win[4]  = dpp_shr<1>(hr.x); win[5]  = dpp_shr<1>(hr.y);
            win[6]  = dpp_shr<1>(hr.z); win[7]  = dpp_shr<1>(hr.w);
            win[12] = dpp_shl<1>(hr.x); win[13] = dpp_shl<1>(hr.y);
            win[14] = dpp_shl<1>(hr.z); win[15] = dpp_shl<1>(hr.w);
            win[16] = dpp_shl<2>(hr.x); win[17] = dpp_shl<2>(hr.y);
            win[18] = dpp_shl<2>(hr.z); win[19] = dpp_shl<2>(hr.w);
            float4 qv;
            qv.x = c0 * win[8];  qv.y = c0 * win[9];
            qv.z = c0 * win[10]; qv.w = c0 * win[11];
#pragma unroll
            for (int k = 1; k <= 7; ++k) {
                float c = cg_[n][k];
                qv.x = fmaf(c, win[8 - k]  + win[8 + k],  qv.x);
                qv.y = fmaf(c, win[9 - k]  + win[9 + k],  qv.y);
                qv.z = fmaf(c, win[10 - k] + win[10 + k], qv.z);
                qv.w = fmaf(c, win[11 - k] + win[11 + k], qv.w);
            }
            if (n == 0) {
#pragma unroll
                for (int j = 0; j < 5; ++j) {
                    float cz = cz_[0][j];
                    u[j].x = cz * qv.x; u[j].y = cz * qv.y;
                    u[j].z = cz * qv.z; u[j].w = cz * qv.w;
                }
            } else {
#pragma unroll
                for (int j = 0; j < 5; ++j)
                    u[j] = f4fma(cz_[n][j], qv, u[j]);
            }
        }
        acc[4] = f4add(acc[4], u[0]);
#pragma unroll
        for (int j = 1; j <= 4; ++j) {
            acc[4 + j] = f4add(acc[4 + j], u[j]);
            acc[4 - j] = f4add(acc[4 - j], u[j]);
        }
    };
    // store completed plane p (output z = z0 + p - 8), then advance the ring
    auto store_shift = [&](int p) {
        if (p >= 8 && qreal) {
            int z = z0 + (p - 8);
            size_t o = ((size_t)(b * D_ + z) * H_ + (h0 + r1)) * W_ + (w0 - 8 + 4 * q);
            *(float4*)&out[o] = acc[0];
        }
#pragma unroll
        for (int k = 0; k < 8; ++k) acc[k] = acc[k + 1];
        acc[8] = z4;
    };

#pragma unroll 1
    for (int i = 0; i < NITER; ++i) {
        __syncthreads();   // pair (i&1) staged; pair ((i+1)&1) free

        const int pA = 2 * i;
        const int ziA = z0 - 4 + pA;
        const int bA = (i & 1) * 2;
        const int znC = ziA + 2, znD = ziA + 3;
        const bool vC = (pA + 2 < NP) && (znC >= 0) && (znC < D_);
        const bool vD = (pA + 3 < NP) && (znD >= 0) && (znD < D_);

        // prefetch next two planes into registers (hidden under this iter)
        float4 cv0, cv1, cv2, dv0, dv1, dv2;
        if (vC) {
            const float* xp = xb + (size_t)znC * HW_;
            cv0 = (goff[0] >= 0) ? *(const float4*)(xp + goff[0]) : z4;
            cv1 = (goff[1] >= 0) ? *(const float4*)(xp + goff[1]) : z4;
            cv2 = z4;
            if (goff[2] >= 0) cv2 = *(const float4*)(xp + goff[2]);
        }
        if (vD) {
            const float* xp = xb + (size_t)znD * HW_;
            dv0 = (goff[0] >= 0) ? *(const float4*)(xp + goff[0]) : z4;
            dv1 = (goff[1] >= 0) ? *(const float4*)(xp + goff[1]) : z4;
            dv2 = z4;
            if (goff[2] >= 0) dv2 = *(const float4*)(xp + goff[2]);
        }

        // two independent plane pipelines (scheduler interleaves reads/math)
        do_plane(ziA, bA);
        store_shift(pA);
        do_plane(ziA + 1, bA + 1);
        store_shift(pA + 1);

        // write prefetched planes into the other buffer pair
        const int bC = ((i + 1) & 1) * 2;
        if (vC) {
            float4* xn = (float4*)(xtb + bC * XT_SZ);
            xn[t] = cv0; xn[t + 192] = cv1;
            if (goff[2] != -2) xn[t + 384] = cv2;
        }
        if (vD) {
            float4* xn = (float4*)(xtb + (bC + 1) * XT_SZ);
            xn[t] = dv0; xn[t + 192] = dv1;
            if (goff[2] != -2) xn[t + 384] = dv2;
        }
    }
}

extern "C" void kernel_launch(void* const* d_in, const int* in_sizes, int n_in,
                              void* d_out, int out_size, void* d_ws, size_t ws_size,
                              hipStream_t stream) {
    const float* x      = (const float*)d_in[0];
    const float* bet_xy = (const float*)d_in[1];
    const float* bet_z  = (const float*)d_in[2];
    const float* alpha  = (const float*)d_in[3];
    float* out = (float*)d_out;

    dim3 grid(W_ / TW, H_ / TH, B_ * (D_ / ZCHUNK));
    if (d_ws != nullptr && ws_size >= WS_FLOATS * sizeof(float)) {
        hipLaunchKernelGGL(psf_precompute, dim3(1), dim3(1024), 0, stream,
                           bet_xy, bet_z, alpha, (float*)d_ws);
        hipLaunchKernelGGL(HIP_KERNEL_NAME(conv_kernel<true>), grid, dim3(NTHR),
                           0, stream, x, bet_xy, bet_z, alpha,
                           (const float*)d_ws, out);
    } else {
        hipLaunchKernelGGL(HIP_KERNEL_NAME(conv_kernel<false>), grid, dim3(NTHR),
                           0, stream, x, bet_xy, bet_z, alpha,
                           (const float*)nullptr, out);
    }
}